// Round 12
// baseline (36.702 us; speedup 1.0000x reference)
//
#include <hip/hip_runtime.h>
#include <cfloat>

// Problem dims (fixed by reference)
#define BB   256   // batch
#define DIM  512
#define NN   196
#define BT   8     // b-tile in prep kernel
#define IT   64    // i-tile in prep kernel (2 i per thread)

// ---------------------------------------------------------------------------
// Kernel 1: prep v5 — w[b,i] = (mem[b,i] + b_mem[i]) * v1[b,i] + v2[b,i]
//   mem[b,i] = sum_k memory[-1][b,k] * W_mem[k,i]
//   v1[b,i]  = sum_k u[b,k] * W_concat[i,     k]   (u = control[-1]*W_attn)
//   v2[b,i]  = sum_k u[b,k] * W_concat[DIM+i, k]
//
// r11 post-mortem: prep is LDS-READ-THROUGHPUT bound (4 b128 MU broadcasts
// per 24 FMA ≈ 24.6K LDS-cyc/CU vs 6.1K FMA-cyc). Fix: 2 i-columns per
// thread -> same MU reads feed 48 FMA (b128 insts/CU halved).
// grid (BB/8, DIM/64) = (32,8) = 256 blocks x 512 thr (8 waves/CU).
// Thread (il=tid&31, kg=tid>>5): i in {i0+il, i0+32+il}, k-slice 4/chunk,
// 8 b -> 48 accumulators. W_concat + W_mem register-prefetched (r11).
// ---------------------------------------------------------------------------
__global__ __launch_bounds__(512, 2) void prep_kernel(
    const float* __restrict__ memory,    // (2,BB,DIM)
    const float* __restrict__ control,   // (2,BB,DIM)
    const float* __restrict__ W_mem,     // (DIM,DIM) row-major [k][i]
    const float* __restrict__ b_mem,     // (DIM)
    const float* __restrict__ W_concat,  // (2*DIM, DIM) row-major [c][j]
    const float* __restrict__ W_attn,    // (DIM,1)
    float* __restrict__ w_out)           // (BB, DIM)
{
    // float arena, 67 KB:
    //   [0, 8192)      MU: float4[4][512]  (m,u for 8 b; pair p covers b0+2p, b0+2p+1)
    //   [8192, 16768)  WT: float2[64][67]  ((c1,c2); col = i_local 0..63; odd stride)
    // epilogue reuses [0, 8192) as P[16 kg][8 b][64 i_local], one acc at a time
    __shared__ float lds[16768];
    float4* MU = (float4*)lds;
    float2* WT = (float2*)(lds + 8192);

    const int tid = threadIdx.x;
    const int il  = tid & 31;          // i_lo = i0+il, i_hi = i0+32+il
    const int kg  = tid >> 5;          // 0..15, owns k-slice kg*4..kg*4+3 per chunk
    const int b0  = blockIdx.x * BT;
    const int i0  = blockIdx.y * IT;

    const float* mem_in = memory  + (size_t)BB * DIM;  // memory[-1]
    const float* ctl_in = control + (size_t)BB * DIM;  // control[-1]

    // ---- stage MU once (coalesced over k = tid) ----
    {
        const float wa = W_attn[tid];
        #pragma unroll
        for (int p = 0; p < 4; ++p) {
            MU[p * 512 + tid] = make_float4(
                mem_in[(size_t)(b0 + 2 * p)     * DIM + tid],
                ctl_in[(size_t)(b0 + 2 * p)     * DIM + tid] * wa,
                mem_in[(size_t)(b0 + 2 * p + 1) * DIM + tid],
                ctl_in[(size_t)(b0 + 2 * p + 1) * DIM + tid] * wa);
        }
    }

    // ---- W_concat / W_mem register prefetch (chunk 0) ----
    const int sr = tid >> 4;           // 0..31 source i-row within 32-row group
    const int sc = tid & 15;           // 0..15 f4-col of the 64-k chunk
    const float* w1l = W_concat + (size_t)(i0 + sr)            * DIM;
    const float* w2l = W_concat + (size_t)(DIM + i0 + sr)      * DIM;
    const float* w1h = W_concat + (size_t)(i0 + 32 + sr)       * DIM;
    const float* w2h = W_concat + (size_t)(DIM + i0 + 32 + sr) * DIM;

    float4 f1l = *(const float4*)(w1l + sc * 4);
    float4 f2l = *(const float4*)(w2l + sc * 4);
    float4 f1h = *(const float4*)(w1h + sc * 4);
    float4 f2h = *(const float4*)(w2h + sc * 4);

    float wmc[4][2], wmn[4][2];
    #pragma unroll
    for (int j = 0; j < 4; ++j) {
        wmc[j][0] = W_mem[(size_t)(kg * 4 + j) * DIM + i0 + il];
        wmc[j][1] = W_mem[(size_t)(kg * 4 + j) * DIM + i0 + 32 + il];
    }

    float am[8][2] = {}, a1[8][2] = {}, a2[8][2] = {};

    for (int kt = 0; kt < DIM; kt += 64) {
        __syncthreads();   // prev chunk's compute done; WT free

        // write prefetched W_concat regs -> WT (transposed, (c1,c2) pairs)
        {
            const float* pa = (const float*)&f1l;
            const float* pb = (const float*)&f2l;
            const float* pc = (const float*)&f1h;
            const float* pd = (const float*)&f2h;
            #pragma unroll
            for (int cc = 0; cc < 4; ++cc) {
                const int k = sc * 4 + cc;
                WT[k * 67 + sr]      = make_float2(pa[cc], pb[cc]);
                WT[k * 67 + 32 + sr] = make_float2(pc[cc], pd[cc]);
            }
        }
        // issue next chunk's W_concat loads (hide under this chunk's compute)
        if (kt + 64 < DIM) {
            f1l = *(const float4*)(w1l + kt + 64 + sc * 4);
            f2l = *(const float4*)(w2l + kt + 64 + sc * 4);
            f1h = *(const float4*)(w1h + kt + 64 + sc * 4);
            f2h = *(const float4*)(w2h + kt + 64 + sc * 4);
        }
        __syncthreads();

        // issue next chunk's W_mem loads early
        if (kt + 64 < DIM) {
            #pragma unroll
            for (int j = 0; j < 4; ++j) {
                wmn[j][0] = W_mem[(size_t)(kt + 64 + kg * 4 + j) * DIM + i0 + il];
                wmn[j][1] = W_mem[(size_t)(kt + 64 + kg * 4 + j) * DIM + i0 + 32 + il];
            }
        }

        // compute: 4 k-steps, 48 FMA per step, 3 LDS reads (2 b128 mu via
        // 4 f4 dual-addr + 2 b64 c) amortized over 2 i-columns
        #pragma unroll
        for (int j = 0; j < 4; ++j) {
            const int kl = kg * 4 + j;
            const int k  = kt + kl;
            const float2 cl = WT[kl * 67 + il];        // (c1,c2) @ i_lo
            const float2 ch = WT[kl * 67 + 32 + il];   // (c1,c2) @ i_hi
            #pragma unroll
            for (int p = 0; p < 4; ++p) {
                const float4 mu = MU[p * 512 + k];     // broadcast b128
                am[2*p][0]   = fmaf(mu.x, wmc[j][0], am[2*p][0]);
                am[2*p][1]   = fmaf(mu.x, wmc[j][1], am[2*p][1]);
                a1[2*p][0]   = fmaf(mu.y, cl.x, a1[2*p][0]);
                a1[2*p][1]   = fmaf(mu.y, ch.x, a1[2*p][1]);
                a2[2*p][0]   = fmaf(mu.y, cl.y, a2[2*p][0]);
                a2[2*p][1]   = fmaf(mu.y, ch.y, a2[2*p][1]);
                am[2*p+1][0] = fmaf(mu.z, wmc[j][0], am[2*p+1][0]);
                am[2*p+1][1] = fmaf(mu.z, wmc[j][1], am[2*p+1][1]);
                a1[2*p+1][0] = fmaf(mu.w, cl.x, a1[2*p+1][0]);
                a1[2*p+1][1] = fmaf(mu.w, ch.x, a1[2*p+1][1]);
                a2[2*p+1][0] = fmaf(mu.w, cl.y, a2[2*p+1][0]);
                a2[2*p+1][1] = fmaf(mu.w, ch.y, a2[2*p+1][1]);
            }
        }
        #pragma unroll
        for (int j = 0; j < 4; ++j) {
            wmc[j][0] = wmn[j][0];
            wmc[j][1] = wmn[j][1];
        }
    }

    // ---- epilogue: 3 phases, reduce 16 kg-partials per acc type ----
    // P row = (kg*8 + b)*64 + i_local ; reader tid: rb = tid>>6, ilo = tid&63
    const int rb  = tid >> 6;
    const int ilo = tid & 63;
    float sm, s1v, s2v;

    __syncthreads();
    #pragma unroll
    for (int b = 0; b < 8; ++b) {
        lds[(kg * 8 + b) * 64 + il]      = am[b][0];
        lds[(kg * 8 + b) * 64 + 32 + il] = am[b][1];
    }
    __syncthreads();
    sm = 0.f;
    #pragma unroll
    for (int t = 0; t < 16; ++t) sm += lds[(t * 8 + rb) * 64 + ilo];

    __syncthreads();
    #pragma unroll
    for (int b = 0; b < 8; ++b) {
        lds[(kg * 8 + b) * 64 + il]      = a1[b][0];
        lds[(kg * 8 + b) * 64 + 32 + il] = a1[b][1];
    }
    __syncthreads();
    s1v = 0.f;
    #pragma unroll
    for (int t = 0; t < 16; ++t) s1v += lds[(t * 8 + rb) * 64 + ilo];

    __syncthreads();
    #pragma unroll
    for (int b = 0; b < 8; ++b) {
        lds[(kg * 8 + b) * 64 + il]      = a2[b][0];
        lds[(kg * 8 + b) * 64 + 32 + il] = a2[b][1];
    }
    __syncthreads();
    s2v = 0.f;
    #pragma unroll
    for (int t = 0; t < 16; ++t) s2v += lds[(t * 8 + rb) * 64 + ilo];

    w_out[(size_t)(b0 + rb) * DIM + i0 + ilo] =
        (sm + b_mem[i0 + ilo]) * s1v + s2v;
}

// ---------------------------------------------------------------------------
// Kernel 2: per-b streaming pass over know (float4, 16 waves/block).
// (byte-identical to round 6 — best proven read)
// ---------------------------------------------------------------------------
__global__ __launch_bounds__(1024) void read_kernel(
    const float* __restrict__ know,  // (BB, DIM, NN)
    const float* __restrict__ w,     // (BB, DIM)
    float* __restrict__ out)         // (BB, NN)
{
    __shared__ float  w_s[DIM];
    __shared__ float4 part_lg[16][50];
    __shared__ float4 part_ks[16][50];
    __shared__ float  tmp[256];
    __shared__ float  bc[2];

    const int tx  = threadIdx.x;       // 0..63 (lane)
    const int ty  = threadIdx.y;       // 0..15 (wave)
    const int tid = ty * 64 + tx;
    const int b   = blockIdx.x;

    if (tid < DIM) w_s[tid] = w[(size_t)b * DIM + tid];
    __syncthreads();

    float4 lg = make_float4(0.f, 0.f, 0.f, 0.f);
    float4 ks = make_float4(0.f, 0.f, 0.f, 0.f);
    if (tx < 49) {
        const float4* kp = (const float4*)(know + (size_t)b * DIM * NN) + (size_t)(ty * 32) * 49 + tx;
        const float*  wp = w_s + ty * 32;
        #pragma unroll 8
        for (int dd = 0; dd < 32; ++dd) {
            const float4 kv = kp[(size_t)dd * 49];
            const float  wv = wp[dd];
            lg.x = fmaf(kv.x, wv, lg.x); lg.y = fmaf(kv.y, wv, lg.y);
            lg.z = fmaf(kv.z, wv, lg.z); lg.w = fmaf(kv.w, wv, lg.w);
            ks.x += kv.x; ks.y += kv.y; ks.z += kv.z; ks.w += kv.w;
        }
        part_lg[ty][tx] = lg;
        part_ks[ty][tx] = ks;
    }
    __syncthreads();

    float lgn = 0.f, ksn = 0.f;
    if (tid < NN) {
        const int ng = tid >> 2, j = tid & 3;
        #pragma unroll
        for (int t = 0; t < 16; ++t) {
            lgn += ((const float*)&part_lg[t][ng])[j];
            ksn += ((const float*)&part_ks[t][ng])[j];
        }
    }

    if (tid < 256) tmp[tid] = (tid < NN) ? lgn : -FLT_MAX;
    __syncthreads();
    if (tid < 64) {
        float m = fmaxf(fmaxf(tmp[tid], tmp[tid + 64]),
                        fmaxf(tmp[tid + 128], tmp[tid + 192]));
        #pragma unroll
        for (int o = 32; o; o >>= 1) m = fmaxf(m, __shfl_down(m, o));
        if (tid == 0) bc[0] = m;
    }
    __syncthreads();

    const float e = (tid < NN) ? __expf(lgn - bc[0]) : 0.f;
    if (tid < 256) tmp[tid] = e;
    __syncthreads();
    if (tid < 64) {
        float s = tmp[tid] + tmp[tid + 64] + tmp[tid + 128] + tmp[tid + 192];
        #pragma unroll
        for (int o = 32; o; o >>= 1) s += __shfl_down(s, o);
        if (tid == 0) bc[1] = s;
    }
    __syncthreads();

    if (tid < NN) out[(size_t)b * NN + tid] = e / bc[1] * ksn;
}

// ---------------------------------------------------------------------------
extern "C" void kernel_launch(void* const* d_in, const int* in_sizes, int n_in,
                              void* d_out, int out_size, void* d_ws, size_t ws_size,
                              hipStream_t stream) {
    const float* memory   = (const float*)d_in[0];
    const float* know     = (const float*)d_in[1];
    const float* control  = (const float*)d_in[2];
    const float* W_mem    = (const float*)d_in[3];
    const float* b_mem    = (const float*)d_in[4];
    const float* W_concat = (const float*)d_in[5];
    // d_in[6] = b_concat : uniform over n -> softmax-invariant, unused
    const float* W_attn   = (const float*)d_in[7];
    // d_in[8] = b_attn   : same, unused
    float* w_ws = (float*)d_ws;          // (BB, DIM) = 512 KB scratch
    float* outp = (float*)d_out;         // (BB, NN) f32

    prep_kernel<<<dim3(BB / BT, DIM / IT), dim3(512), 0, stream>>>(
        memory, control, W_mem, b_mem, W_concat, W_attn, w_ws);
    read_kernel<<<dim3(BB), dim3(64, 16), 0, stream>>>(know, w_ws, outp);
}

// Round 13
// 33.121 us; speedup vs baseline: 1.1081x; 1.1081x over previous
//
#include <hip/hip_runtime.h>
#include <cfloat>

// Problem dims (fixed by reference)
#define BB   256   // batch
#define DIM  512
#define NN   196

typedef __attribute__((ext_vector_type(8))) short bf16x8;   // 8 bf16 (4 VGPRs)
typedef __attribute__((ext_vector_type(4))) float f32x4;    // MFMA acc

__device__ __forceinline__ ushort f2bf(float x) {          // RNE f32->bf16
    unsigned u = __float_as_uint(x);
    return (ushort)((u + 0x7FFFu + ((u >> 16) & 1u)) >> 16);
}

// ---------------------------------------------------------------------------
// Kernel 0: convert — build bf16 operands in d_ws.
//   Wt[0][i][k] = bf16(W_mem[k][i])      (transposed -> [i][k])
//   Wt[1][i][k] = bf16(W_concat[i][k])   ; Wt[2][i][k] = bf16(W_concat[DIM+i][k])
//   mu[0][b][k] = bf16(memory[-1][b][k]) ; mu[1][b][k] = bf16(ctl[-1][b][k]*W_attn[k])
// grid 256 x 256: blocks 0-127 Wc, 128-191 WmT (64x64 LDS transpose), 192-255 mu.
// ---------------------------------------------------------------------------
__global__ __launch_bounds__(256) void convert_kernel(
    const float* __restrict__ memory, const float* __restrict__ control,
    const float* __restrict__ W_mem, const float* __restrict__ W_concat,
    const float* __restrict__ W_attn,
    ushort* __restrict__ Wt,      // [3][512][512] bf16
    ushort* __restrict__ mu)      // [2][256][512] bf16
{
    const int tid = threadIdx.x;
    const int blk = blockIdx.x;

    if (blk < 128) {
        // ---- W_concat straight convert: 131072 float4 -> uint2 ----
        const float4* in4 = (const float4*)W_concat;
        uint2* out = (uint2*)(Wt + (size_t)DIM * DIM);   // mats 1,2 contiguous
        #pragma unroll
        for (int p = 0; p < 4; ++p) {
            const int idx = blk * 1024 + p * 256 + tid;  // 0..131071
            const float4 q = in4[idx];
            uint2 o;
            o.x = (unsigned)f2bf(q.x) | ((unsigned)f2bf(q.y) << 16);
            o.y = (unsigned)f2bf(q.z) | ((unsigned)f2bf(q.w) << 16);
            out[idx] = o;
        }
    } else if (blk < 192) {
        // ---- W_mem transpose-convert, 64x64 tile via LDS ----
        __shared__ float T[64][65];
        const int t  = blk - 128;
        const int tk = (t >> 3) * 64, ti = (t & 7) * 64;
        const int r  = tid >> 2;            // k-local row
        const int cb = (tid & 3) * 16;      // i-local col base
        #pragma unroll
        for (int j = 0; j < 16; j += 4) {
            const float4 q = *(const float4*)&W_mem[(size_t)(tk + r) * DIM + ti + cb + j];
            T[r][cb + j + 0] = q.x; T[r][cb + j + 1] = q.y;
            T[r][cb + j + 2] = q.z; T[r][cb + j + 3] = q.w;
        }
        __syncthreads();
        const int ii = tid & 63;            // i-local
        const int kq = tid >> 6;            // 0..3
        #pragma unroll
        for (int kk = 0; kk < 16; kk += 2) {
            const int k = kq * 16 + kk;
            const unsigned v = (unsigned)f2bf(T[k][ii]) | ((unsigned)f2bf(T[k + 1][ii]) << 16);
            *(unsigned*)&Wt[(size_t)(ti + ii) * DIM + tk + k] = v;
        }
    } else {
        // ---- m / u convert: 2 x 32768 float4 ----
        const float4* mem4 = (const float4*)(memory  + (size_t)BB * DIM);
        const float4* ctl4 = (const float4*)(control + (size_t)BB * DIM);
        const float4* wa4  = (const float4*)W_attn;
        uint2* out = (uint2*)mu;
        #pragma unroll
        for (int p = 0; p < 4; ++p) {
            const int idx = (blk - 192) * 1024 + p * 256 + tid;  // 0..65535
            const int sec = idx >> 15;        // 0 = m, 1 = u
            const int j   = idx & 32767;      // f4 index within section
            float4 q = sec ? ctl4[j] : mem4[j];
            if (sec) {
                const float4 wa = wa4[j & 127];
                q.x *= wa.x; q.y *= wa.y; q.z *= wa.z; q.w *= wa.w;
            }
            uint2 o;
            o.x = (unsigned)f2bf(q.x) | ((unsigned)f2bf(q.y) << 16);
            o.y = (unsigned)f2bf(q.z) | ((unsigned)f2bf(q.w) << 16);
            out[(size_t)sec * 32768 + j] = o;
        }
    }
}

// ---------------------------------------------------------------------------
// Kernel 1: prep via MFMA — w[b,i] = (mem[b,i]+b_mem[i])*v1[b,i] + v2[b,i]
// Three GEMMs D[b,i] = A[b,k]·B[k,i] with A in {m,u}, B = Wt rows (the MFMA
// B-fragment is k-sliced per lane, so row-major [i][k] loads directly — no
// transpose). 16x16x32 bf16, 16 k-steps, 3 MFMA per step, f32 accumulate.
// grid (BB/16, DIM/32) = (16,16) x 128 thr (2 waves; wave = one 16i sub-tile).
// Fragment maps (m89-verified): A lane l -> row=l&15, k=8*(l>>4)+j ;
// B lane l -> col=l&15, k same ; D lane l -> col=l&15, row=4*(l>>4)+reg.
// ---------------------------------------------------------------------------
__global__ __launch_bounds__(128) void prep_mfma(
    const ushort* __restrict__ Wt,    // [3][512][512] bf16
    const ushort* __restrict__ mu,    // [2][256][512] bf16
    const float* __restrict__ b_mem,  // (DIM)
    float* __restrict__ w_out)        // (BB, DIM)
{
    __shared__ __align__(16) ushort mus[2][16][520];   // +8 pad: row stride 1040B

    const int tid = threadIdx.x;     // 0..127
    const int wv  = tid >> 6;        // wave 0..1
    const int l   = tid & 63;        // lane
    const int b0  = blockIdx.x * 16;
    const int i0  = blockIdx.y * 32;

    // stage m,u for 16 b rows: 2048 uint4 by 128 threads
    #pragma unroll
    for (int p = 0; p < 16; ++p) {
        const int idx = p * 128 + tid;        // 0..2047
        const int a   = idx >> 10;            // 0..1 (m / u)
        const int rb  = (idx >> 6) & 15;      // b row
        const int kc  = (idx & 63) * 8;       // k offset (ushorts)
        *(uint4*)&mus[a][rb][kc] =
            *(const uint4*)&mu[((size_t)a * BB + b0 + rb) * DIM + kc];
    }
    __syncthreads();

    const int fr = l & 15;           // A row (b) / B col (i) / D col (i)
    const int fk = (l >> 4) * 8;     // k offset within 32-step

    f32x4 accM = {0.f, 0.f, 0.f, 0.f};
    f32x4 acc1 = {0.f, 0.f, 0.f, 0.f};
    f32x4 acc2 = {0.f, 0.f, 0.f, 0.f};

    const int ib = i0 + wv * 16 + fr;                    // this lane's i
    const ushort* wm = Wt + ((size_t)0 * DIM + ib) * DIM;
    const ushort* c1 = Wt + ((size_t)1 * DIM + ib) * DIM;
    const ushort* c2 = Wt + ((size_t)2 * DIM + ib) * DIM;

    #pragma unroll 4
    for (int t = 0; t < 16; ++t) {
        const int k = t * 32 + fk;
        const bf16x8 am = *(const bf16x8*)&mus[0][fr][k];
        const bf16x8 au = *(const bf16x8*)&mus[1][fr][k];
        const bf16x8 bm = *(const bf16x8*)&wm[k];
        const bf16x8 b1 = *(const bf16x8*)&c1[k];
        const bf16x8 b2 = *(const bf16x8*)&c2[k];
        accM = __builtin_amdgcn_mfma_f32_16x16x32_bf16(am, bm, accM, 0, 0, 0);
        acc1 = __builtin_amdgcn_mfma_f32_16x16x32_bf16(au, b1, acc1, 0, 0, 0);
        acc2 = __builtin_amdgcn_mfma_f32_16x16x32_bf16(au, b2, acc2, 0, 0, 0);
    }

    const float bmv = b_mem[ib];
    const int rb0 = (l >> 4) * 4;
    #pragma unroll
    for (int r = 0; r < 4; ++r) {
        w_out[(size_t)(b0 + rb0 + r) * DIM + ib] =
            (accM[r] + bmv) * acc1[r] + acc2[r];
    }
}

// ---------------------------------------------------------------------------
// Kernel 1-fallback (r11-proven f32 prep) — only if ws_size too small.
// ---------------------------------------------------------------------------
__global__ __launch_bounds__(512, 4) void prep_fallback(
    const float* __restrict__ memory, const float* __restrict__ control,
    const float* __restrict__ W_mem, const float* __restrict__ b_mem,
    const float* __restrict__ W_concat, const float* __restrict__ W_attn,
    float* __restrict__ w_out)
{
    __shared__ float4 MU4[4][DIM];
    __shared__ float  buf[12288];

    const int tid = threadIdx.x;
    const int il  = tid & 31;
    const int kg  = tid >> 5;
    const int b0  = blockIdx.x * 8;
    const int i0  = blockIdx.y * 32;

    const float* mem_in = memory  + (size_t)BB * DIM;
    const float* ctl_in = control + (size_t)BB * DIM;

    {
        const float wa = W_attn[tid];
        #pragma unroll
        for (int p = 0; p < 4; ++p) {
            MU4[p][tid] = make_float4(
                mem_in[(size_t)(b0 + 2 * p)     * DIM + tid],
                ctl_in[(size_t)(b0 + 2 * p)     * DIM + tid] * wa,
                mem_in[(size_t)(b0 + 2 * p + 1) * DIM + tid],
                ctl_in[(size_t)(b0 + 2 * p + 1) * DIM + tid] * wa);
        }
    }

    float am[8] = {}, a1[8] = {}, a2[8] = {};
    const int sr = tid >> 4;
    const int sc = tid & 15;
    float2* WT = (float2*)buf;

    float4 f1 = *(const float4*)&W_concat[(size_t)(i0 + sr) * DIM + sc * 4];
    float4 f2 = *(const float4*)&W_concat[(size_t)(DIM + i0 + sr) * DIM + sc * 4];
    float wmc[4], wmn[4];
    #pragma unroll
    for (int j = 0; j < 4; ++j)
        wmc[j] = W_mem[(size_t)(kg * 4 + j) * DIM + i0 + il];

    for (int kt = 0; kt < DIM; kt += 64) {
        __syncthreads();
        {
            const float* f1f = (const float*)&f1;
            const float* f2f = (const float*)&f2;
            #pragma unroll
            for (int j = 0; j < 4; ++j)
                WT[(sc * 4 + j) * 33 + sr] = make_float2(f1f[j], f2f[j]);
        }
        if (kt + 64 < DIM) {
            f1 = *(const float4*)&W_concat[(size_t)(i0 + sr) * DIM + kt + 64 + sc * 4];
            f2 = *(const float4*)&W_concat[(size_t)(DIM + i0 + sr) * DIM + kt + 64 + sc * 4];
        }
        __syncthreads();
        if (kt + 64 < DIM) {
            #pragma unroll
            for (int j = 0; j < 4; ++j)
                wmn[j] = W_mem[(size_t)(kt + 64 + kg * 4 + j) * DIM + i0 + il];
        }
        #pragma unroll
        for (int j = 0; j < 4; ++j) {
            const int kl = kg * 4 + j;
            const int k  = kt + kl;
            const float2 c = WT[kl * 33 + il];
            #pragma unroll
            for (int p = 0; p < 4; ++p) {
                const float4 muv = MU4[p][k];
                am[2*p]   = fmaf(muv.x, wmc[j], am[2*p]);
                a1[2*p]   = fmaf(muv.y, c.x,    a1[2*p]);
                a2[2*p]   = fmaf(muv.y, c.y,    a2[2*p]);
                am[2*p+1] = fmaf(muv.z, wmc[j], am[2*p+1]);
                a1[2*p+1] = fmaf(muv.w, c.x,    a1[2*p+1]);
                a2[2*p+1] = fmaf(muv.w, c.y,    a2[2*p+1]);
            }
        }
        #pragma unroll
        for (int j = 0; j < 4; ++j) wmc[j] = wmn[j];
    }

    __syncthreads();
    #pragma unroll
    for (int b = 0; b < 8; ++b) {
        const int row = (kg * 8 + b) * 32 + il;
        buf[row]        = am[b];
        buf[4096 + row] = a1[b];
        buf[8192 + row] = a2[b];
    }
    __syncthreads();
    if (tid < 256) {
        const int rb = tid >> 5, ri = tid & 31;
        float sm = 0.f, s1 = 0.f, s2 = 0.f;
        #pragma unroll
        for (int t = 0; t < 16; ++t) {
            const int row = (t * 8 + rb) * 32 + ri;
            sm += buf[row];
            s1 += buf[4096 + row];
            s2 += buf[8192 + row];
        }
        w_out[(size_t)(b0 + rb) * DIM + i0 + ri] =
            (sm + b_mem[i0 + ri]) * s1 + s2;
    }
}

// ---------------------------------------------------------------------------
// Kernel 2: per-b streaming pass over know (float4, 16 waves/block).
// (byte-identical to round 6 — best proven read)
// ---------------------------------------------------------------------------
__global__ __launch_bounds__(1024) void read_kernel(
    const float* __restrict__ know,  // (BB, DIM, NN)
    const float* __restrict__ w,     // (BB, DIM)
    float* __restrict__ out)         // (BB, NN)
{
    __shared__ float  w_s[DIM];
    __shared__ float4 part_lg[16][50];
    __shared__ float4 part_ks[16][50];
    __shared__ float  tmp[256];
    __shared__ float  bc[2];

    const int tx  = threadIdx.x;       // 0..63 (lane)
    const int ty  = threadIdx.y;       // 0..15 (wave)
    const int tid = ty * 64 + tx;
    const int b   = blockIdx.x;

    if (tid < DIM) w_s[tid] = w[(size_t)b * DIM + tid];
    __syncthreads();

    float4 lg = make_float4(0.f, 0.f, 0.f, 0.f);
    float4 ks = make_float4(0.f, 0.f, 0.f, 0.f);
    if (tx < 49) {
        const float4* kp = (const float4*)(know + (size_t)b * DIM * NN) + (size_t)(ty * 32) * 49 + tx;
        const float*  wp = w_s + ty * 32;
        #pragma unroll 8
        for (int dd = 0; dd < 32; ++dd) {
            const float4 kv = kp[(size_t)dd * 49];
            const float  wv = wp[dd];
            lg.x = fmaf(kv.x, wv, lg.x); lg.y = fmaf(kv.y, wv, lg.y);
            lg.z = fmaf(kv.z, wv, lg.z); lg.w = fmaf(kv.w, wv, lg.w);
            ks.x += kv.x; ks.y += kv.y; ks.z += kv.z; ks.w += kv.w;
        }
        part_lg[ty][tx] = lg;
        part_ks[ty][tx] = ks;
    }
    __syncthreads();

    float lgn = 0.f, ksn = 0.f;
    if (tid < NN) {
        const int ng = tid >> 2, j = tid & 3;
        #pragma unroll
        for (int t = 0; t < 16; ++t) {
            lgn += ((const float*)&part_lg[t][ng])[j];
            ksn += ((const float*)&part_ks[t][ng])[j];
        }
    }

    if (tid < 256) tmp[tid] = (tid < NN) ? lgn : -FLT_MAX;
    __syncthreads();
    if (tid < 64) {
        float m = fmaxf(fmaxf(tmp[tid], tmp[tid + 64]),
                        fmaxf(tmp[tid + 128], tmp[tid + 192]));
        #pragma unroll
        for (int o = 32; o; o >>= 1) m = fmaxf(m, __shfl_down(m, o));
        if (tid == 0) bc[0] = m;
    }
    __syncthreads();

    const float e = (tid < NN) ? __expf(lgn - bc[0]) : 0.f;
    if (tid < 256) tmp[tid] = e;
    __syncthreads();
    if (tid < 64) {
        float s = tmp[tid] + tmp[tid + 64] + tmp[tid + 128] + tmp[tid + 192];
        #pragma unroll
        for (int o = 32; o; o >>= 1) s += __shfl_down(s, o);
        if (tid == 0) bc[1] = s;
    }
    __syncthreads();

    if (tid < NN) out[(size_t)b * NN + tid] = e / bc[1] * ksn;
}

// ---------------------------------------------------------------------------
extern "C" void kernel_launch(void* const* d_in, const int* in_sizes, int n_in,
                              void* d_out, int out_size, void* d_ws, size_t ws_size,
                              hipStream_t stream) {
    const float* memory   = (const float*)d_in[0];
    const float* know     = (const float*)d_in[1];
    const float* control  = (const float*)d_in[2];
    const float* W_mem    = (const float*)d_in[3];
    const float* b_mem    = (const float*)d_in[4];
    const float* W_concat = (const float*)d_in[5];
    // d_in[6] = b_concat : uniform over n -> softmax-invariant, unused
    const float* W_attn   = (const float*)d_in[7];
    // d_in[8] = b_attn   : same, unused
    float* outp = (float*)d_out;

    const size_t W_BYTES  = (size_t)BB * DIM * sizeof(float);        // 512 KB
    const size_t WT_BYTES = (size_t)3 * DIM * DIM * sizeof(ushort);  // 1.5 MB
    const size_t MU_BYTES = (size_t)2 * BB * DIM * sizeof(ushort);   // 512 KB

    float* w_ws = (float*)d_ws;

    if (ws_size >= W_BYTES + WT_BYTES + MU_BYTES) {
        ushort* Wt = (ushort*)((char*)d_ws + W_BYTES);
        ushort* mu = (ushort*)((char*)d_ws + W_BYTES + WT_BYTES);
        convert_kernel<<<dim3(256), dim3(256), 0, stream>>>(
            memory, control, W_mem, W_concat, W_attn, Wt, mu);
        prep_mfma<<<dim3(BB / 16, DIM / 32), dim3(128), 0, stream>>>(
            Wt, mu, b_mem, w_ws);
    } else {
        prep_fallback<<<dim3(BB / 8, DIM / 32), dim3(512), 0, stream>>>(
            memory, control, W_mem, b_mem, W_concat, W_attn, w_ws);
    }
    read_kernel<<<dim3(BB), dim3(64, 16), 0, stream>>>(know, w_ws, outp);
}